// Round 5
// baseline (232.104 us; speedup 1.0000x reference)
//
#include <hip/hip_runtime.h>
#include <cstddef>
#include <cstdint>

#define BATCH 128
#define NF 7

typedef float v2f __attribute__((ext_vector_type(2)));

__device__ __forceinline__ v2f silu2(v2f a) {
    v2f t = a * -1.442695041f;
    v2f e;
    e.x = __builtin_amdgcn_exp2f(t.x);
    e.y = __builtin_amdgcn_exp2f(t.y);
    v2f d = e + 1.0f;
    v2f r;
    r.x = __builtin_amdgcn_rcpf(d.x);
    r.y = __builtin_amdgcn_rcpf(d.y);
    return a * r;
}

// feats layout: out[i][f][lane] as float2 {row b, row b+64}
__global__ void feats_kernel(const float* __restrict__ in, float* __restrict__ out,
                             int din, int do_elu) {
    int t = blockIdx.x * blockDim.x + threadIdx.x;
    if (t >= din * BATCH) return;
    int b = t & (BATCH - 1);
    int i = t >> 7;
    float v = in[b * din + i];
    if (do_elu) v = (v > 0.0f) ? v : (__builtin_amdgcn_exp2f(v * 1.442695041f) - 1.0f);
    float s1, c1, s2, c2, s4, c4;
    sincosf(v, &s1, &c1);
    sincosf(2.0f * v, &s2, &c2);
    sincosf(4.0f * v, &s4, &c4);
    float* o = out + (size_t)i * (NF * 128) + (b & 63) * 2 + (b >> 6);
    o[0 * 128] = v;
    o[1 * 128] = s1;
    o[2 * 128] = s2;
    o[3 * 128] = s4;
    o[4 * 128] = c1;
    o[5 * 128] = c2;
    o[6 * 128] = c4;
}

// Scalar-path weights (s_load -> SGPR broadcast via v_fma SGPR operand), software-
// pipelined in groups of 4h with double-buffered SGPR arrays so SMEM latency hides
// under compute. Group = 4 rows of {w0..w6} (28 f) + 4 b1 + 4 w2 = 36 dwords.
//   W[0..27]  = w1 rows, W[28..31] = b1, W[32..35] = w2

#define LOAD_GRP(W, g) do {                                                    \
    _Pragma("unroll")                                                          \
    for (int q = 0; q < 7; ++q)                                                \
        *(float4*)&W[q * 4] = *(const float4*)(w1p + (g) * 28 + q * 4);        \
    *(float4*)&W[28] = *(const float4*)(b1p + (g) * 4);                        \
    *(float4*)&W[32] = *(const float4*)(w2p + (g) * 4);                        \
} while (0)

#define COMP_GRP(W, fbuf) do {                                                 \
    _Pragma("unroll")                                                          \
    for (int hh = 0; hh < 4; ++hh) {                                           \
        v2f a = { W[28 + hh], W[28 + hh] };                                    \
        _Pragma("unroll")                                                      \
        for (int ff = 0; ff < NF; ++ff) {                                      \
            float wv = W[hh * 7 + ff];                                         \
            a.x = fmaf(fbuf[ff].x, wv, a.x);                                   \
            a.y = fmaf(fbuf[ff].y, wv, a.y);                                   \
        }                                                                      \
        v2f s = silu2(a);                                                      \
        o.x = fmaf(s.x, W[32 + hh], o.x);                                      \
        o.y = fmaf(s.y, W[32 + hh], o.y);                                      \
    }                                                                          \
} while (0)

#define TASK_BODY(tt, fcur, fnxt, PREF) do {                                   \
    const int i_ = __builtin_amdgcn_readfirstlane(i0 + (tt) * 4 + w);          \
    const size_t task_ = (size_t)i_ * DOUT + j;                                \
    const float* __restrict__ w1p = W1 + task_ * 224;                          \
    const float* __restrict__ b1p = B1 + task_ * 32;                           \
    const float* __restrict__ w2p = W2 + task_ * 32;                           \
    float WA[36], WB[36];                                                      \
    LOAD_GRP(WA, 0);                                                           \
    if (PREF) {                                                                \
        const int i2_ = __builtin_amdgcn_readfirstlane(i0 + ((tt) + 1) * 4 + w);\
        const float* fp2 = fx + (size_t)i2_ * (NF * 128) + lane * 2;           \
        _Pragma("unroll")                                                      \
        for (int ff = 0; ff < NF; ++ff) fnxt[ff] = *(const v2f*)(fp2 + ff * 128);\
    }                                                                          \
    v2f o = (v2f)(0.0f);                                                       \
    _Pragma("unroll 1")                                                        \
    for (int g = 0; g < 8; g += 2) {                                           \
        LOAD_GRP(WB, g + 1);                                                   \
        COMP_GRP(WA, fcur);                                                    \
        if (g + 2 < 8) LOAD_GRP(WA, g + 2);                                    \
        COMP_GRP(WB, fcur);                                                    \
    }                                                                          \
    float b2v = B2[task_];                                                     \
    tot += o + b2v;                                                            \
} while (0)

template <int DIN, int DOUT, int CHUNK>
__global__ __launch_bounds__(256, 8) void kan_kernel(
    const float* __restrict__ fx,   // [DIN][NF][64] of float2 pairs
    const float* __restrict__ W1,   // [DIN][DOUT][32][7]
    const float* __restrict__ W2,   // [DIN][DOUT][32]
    const float* __restrict__ B1,   // [DIN][DOUT][32]
    const float* __restrict__ B2,   // [DIN][DOUT]
    float* __restrict__ out)        // [BATCH][DOUT], pre-zeroed, atomic accum
{
    __shared__ float redbuf[4 * 128];
    const int j    = blockIdx.x;
    const int tid  = threadIdx.x;
    const int w    = tid >> 6;
    const int lane = tid & 63;
    const int i0   = blockIdx.y * CHUNK;

    v2f tot = (v2f)(0.0f);
    v2f fA[NF], fB[NF];

    {   // prologue: feats for task 0
        const int ip = __builtin_amdgcn_readfirstlane(i0 + w);
        const float* fp = fx + (size_t)ip * (NF * 128) + lane * 2;
        #pragma unroll
        for (int ff = 0; ff < NF; ++ff) fA[ff] = *(const v2f*)(fp + ff * 128);
    }

    #pragma unroll
    for (int t = 0; t < CHUNK / 4; t += 2) {
        TASK_BODY(t,     fA, fB, true);
        TASK_BODY(t + 1, fB, fA, (t + 2 < CHUNK / 4));
    }

    // ---- block-level reduce over the 4 waves, then one atomic per (b, j) ----
    redbuf[w * 128 + lane]      = tot.x;
    redbuf[w * 128 + 64 + lane] = tot.y;
    __syncthreads();
    if (tid < 128) {
        float s = redbuf[tid] + redbuf[128 + tid] + redbuf[256 + tid] + redbuf[384 + tid];
        atomicAdd(&out[(size_t)tid * DOUT + j], s);
    }
}

// GLU gate + residual + BatchNorm(batch axis), one block per output column j.
__device__ __forceinline__ int shidx(int k, int b) { return (k << 7) + ((b + k) & 127); }

__global__ __launch_bounds__(128) void glu_bn_kernel(
    const float* __restrict__ h2,     // [BATCH][128]
    const float* __restrict__ resid,  // [BATCH][128]
    const float* __restrict__ g1w, const float* __restrict__ g1b,
    const float* __restrict__ g2w, const float* __restrict__ g2b,
    const float* __restrict__ bnw, const float* __restrict__ bnb,
    float* __restrict__ out)          // [BATCH][128]
{
    __shared__ float sh[128 * 128];
    const int j   = blockIdx.x;
    const int tid = threadIdx.x;

    for (int b2 = 0; b2 < 128; ++b2)
        sh[shidx(tid, b2)] = h2[(size_t)b2 * 128 + tid];
    __syncthreads();

    const float* g1r = g1w + (size_t)j * 128;
    const float* g2r = g2w + (size_t)j * 128;
    float d1 = g1b[j], d2 = g2b[j];
    for (int k = 0; k < 128; ++k) {
        float hv = sh[shidx(k, tid)];
        d1 = fmaf(hv, g1r[k], d1);
        d2 = fmaf(hv, g2r[k], d2);
    }
    float sg = __builtin_amdgcn_rcpf(1.0f + __builtin_amdgcn_exp2f(d1 * -1.442695041f));
    float v  = sg * d2 + resid[(size_t)tid * 128 + j];

    float s = v, ss = v * v;
    #pragma unroll
    for (int m = 1; m < 64; m <<= 1) {
        s  += __shfl_xor(s,  m, 64);
        ss += __shfl_xor(ss, m, 64);
    }
    __syncthreads();
    if ((tid & 63) == 0) { sh[(tid >> 6) * 2] = s; sh[(tid >> 6) * 2 + 1] = ss; }
    __syncthreads();
    s  = sh[0] + sh[2];
    ss = sh[1] + sh[3];
    float mean = s * (1.0f / 128.0f);
    float var  = ss * (1.0f / 128.0f) - mean * mean;
    out[(size_t)tid * 128 + j] = (v - mean) * rsqrtf(var + 1e-5f) * bnw[j] + bnb[j];
}

extern "C" void kernel_launch(void* const* d_in, const int* in_sizes, int n_in,
                              void* d_out, int out_size, void* d_ws, size_t ws_size,
                              hipStream_t stream) {
    const float* x      = (const float*)d_in[0];
    const float* fc1_W1 = (const float*)d_in[1];
    const float* fc1_W2 = (const float*)d_in[2];
    const float* fc1_B1 = (const float*)d_in[3];
    const float* fc1_B2 = (const float*)d_in[4];
    const float* fc2_W1 = (const float*)d_in[5];
    const float* fc2_W2 = (const float*)d_in[6];
    const float* fc2_B1 = (const float*)d_in[7];
    const float* fc2_B2 = (const float*)d_in[8];
    const float* sk_W1  = (const float*)d_in[9];
    const float* sk_W2  = (const float*)d_in[10];
    const float* sk_B1  = (const float*)d_in[11];
    const float* sk_B2  = (const float*)d_in[12];
    const float* g1w    = (const float*)d_in[13];
    const float* g1b    = (const float*)d_in[14];
    const float* g2w    = (const float*)d_in[15];
    const float* g2b    = (const float*)d_in[16];
    const float* bnw    = (const float*)d_in[17];
    const float* bnb    = (const float*)d_in[18];
    float* out = (float*)d_out;

    float* ws    = (float*)d_ws;
    float* h1    = ws;                    // 128*256
    float* h2    = h1 + 128 * 256;        // 128*128
    float* resid = h2 + 128 * 128;        // 128*128
    float* fx    = resid + 128 * 128;     // 128*7*128
    float* fh    = fx + 128 * NF * 128;   // 256*7*128

    hipMemsetAsync(h1, 0, (size_t)(128 * 256 + 2 * 128 * 128) * sizeof(float), stream);

    feats_kernel<<<dim3((128 * BATCH) / 256), 256, 0, stream>>>(x, fx, 128, 0);

    kan_kernel<128, 256, 16><<<dim3(256, 8), 256, 0, stream>>>(
        fx, fc1_W1, fc1_W2, fc1_B1, fc1_B2, h1);
    kan_kernel<128, 128, 8><<<dim3(128, 16), 256, 0, stream>>>(
        fx, sk_W1, sk_W2, sk_B1, sk_B2, resid);

    feats_kernel<<<dim3((256 * BATCH) / 256), 256, 0, stream>>>(h1, fh, 256, 1);

    kan_kernel<256, 128, 16><<<dim3(128, 16), 256, 0, stream>>>(
        fh, fc2_W1, fc2_W2, fc2_B1, fc2_B2, h2);

    glu_bn_kernel<<<dim3(128), 128, 0, stream>>>(
        h2, resid, g1w, g1b, g2w, g2b, bnw, bnb, out);
}

// Round 6
// 159.180 us; speedup vs baseline: 1.4581x; 1.4581x over previous
//
#include <hip/hip_runtime.h>
#include <hip/hip_bf16.h>
#include <cstddef>
#include <cstdint>

#define NF 7

typedef short bf16x8 __attribute__((ext_vector_type(8)));
typedef float f32x16 __attribute__((ext_vector_type(16)));

__device__ __forceinline__ unsigned short f2bf(float f) {
    union { float f; unsigned u; } v; v.f = f;
    unsigned r = v.u + 0x7fffu + ((v.u >> 16) & 1u);   // round-to-nearest-even
    return (unsigned short)(r >> 16);
}

__device__ __forceinline__ float fast_silu(float a) {
    float e = __builtin_amdgcn_exp2f(a * -1.442695041f);
    return a * __builtin_amdgcn_rcpf(1.0f + e);
}

// feats layout: fxb[i][b][f0..7] bf16, f = {x, sin x, sin 2x, sin 4x, cos x, cos 2x, cos 4x, 1.0}
// (f7 = 1.0 folds B1 into the MFMA as weight slot 7)
__global__ void feats_kernel(const float* __restrict__ in, unsigned short* __restrict__ out,
                             int din, int do_elu) {
    int t = blockIdx.x * blockDim.x + threadIdx.x;
    if (t >= din * 128) return;
    int b = t & 127;
    int i = t >> 7;
    float v = in[b * din + i];
    if (do_elu) v = (v > 0.0f) ? v : (__builtin_amdgcn_exp2f(v * 1.442695041f) - 1.0f);
    float s1, c1, s2, c2, s4, c4;
    sincosf(v, &s1, &c1);
    sincosf(2.0f * v, &s2, &c2);
    sincosf(4.0f * v, &s4, &c4);
    bf16x8 o;
    o[0] = (short)f2bf(v);
    o[1] = (short)f2bf(s1);
    o[2] = (short)f2bf(s2);
    o[3] = (short)f2bf(s4);
    o[4] = (short)f2bf(c1);
    o[5] = (short)f2bf(c2);
    o[6] = (short)f2bf(c4);
    o[7] = (short)0x3F80;           // 1.0 in bf16
    *(bf16x8*)(out + ((size_t)i * 128 + b) * 8) = o;
}

// One wave handles (j, i-chunk). Per i: one MFMA per 32-batch tile computes
// C[h,b] = W1[h,:]·feats[:,b] (+b1 via f7). A-frag: lane<32 row h=lane, k=f 0..7;
// lanes>=32 (k=8..15) are zero-padded. C layout: col=lane&31=b, row=(r&3)+8(r>>2)+4hi=h.
// silu + w2-weighted h-sum on VALU, fp32 accumulation across i, one atomic per (b,j).
template <int DIN, int DOUT, int WCHUNK>
__global__ __launch_bounds__(256, 4) void kan_mfma(
    const unsigned short* __restrict__ fxb,  // [DIN][128][8] bf16
    const float* __restrict__ W1,            // [DIN][DOUT][32][7]
    const float* __restrict__ W2,            // [DIN][DOUT][32]
    const float* __restrict__ B1,            // [DIN][DOUT][32]
    const float* __restrict__ B2,            // [DIN][DOUT]
    float* __restrict__ out)                 // [128][DOUT], pre-zeroed, atomic accum
{
    const int j    = blockIdx.x;
    const int w    = threadIdx.x >> 6;
    const int lane = threadIdx.x & 63;
    const int hl   = lane & 31;
    const int hi   = lane >> 5;
    const int ib   = (blockIdx.y * 4 + w) * WCHUNK;

    float acc0 = 0.f, acc1 = 0.f, acc2 = 0.f, acc3 = 0.f, b2acc = 0.f;

    for (int t = 0; t < WCHUNK; ++t) {
        const int i = ib + t;
        const size_t task = (size_t)i * DOUT + j;

        // ---- A fragment: W1 row h=hl, f=0..6, slot7=b1 (lanes<32); zeros for k=8..15
        bf16x8 A = {0, 0, 0, 0, 0, 0, 0, 0};
        if (hi == 0) {
            const float* wr = W1 + task * 224 + (size_t)hl * 7;
            float b1v = B1[task * 32 + hl];
            A[0] = (short)f2bf(wr[0]);
            A[1] = (short)f2bf(wr[1]);
            A[2] = (short)f2bf(wr[2]);
            A[3] = (short)f2bf(wr[3]);
            A[4] = (short)f2bf(wr[4]);
            A[5] = (short)f2bf(wr[5]);
            A[6] = (short)f2bf(wr[6]);
            A[7] = (short)f2bf(b1v);
        }

        // ---- w2 values for this lane's 16 C regs: h = (r&3) + 8*(r>>2) + 4*hi
        const float* w2p = W2 + task * 32 + hi * 4;
        const float4 w2a = *(const float4*)(w2p);
        const float4 w2b = *(const float4*)(w2p + 8);
        const float4 w2c = *(const float4*)(w2p + 16);
        const float4 w2d = *(const float4*)(w2p + 24);
        const float b2v = B2[task];

        #pragma unroll
        for (int bt = 0; bt < 4; ++bt) {
            bf16x8 Bf = {0, 0, 0, 0, 0, 0, 0, 0};
            if (hi == 0)
                Bf = *(const bf16x8*)(fxb + ((size_t)i * 128 + bt * 32 + hl) * 8);
            f32x16 Cz = {0.f,0.f,0.f,0.f,0.f,0.f,0.f,0.f,0.f,0.f,0.f,0.f,0.f,0.f,0.f,0.f};
            f32x16 C = __builtin_amdgcn_mfma_f32_32x32x16_bf16(A, Bf, Cz, 0, 0, 0);
            float bacc = 0.f;
            #pragma unroll
            for (int r = 0; r < 16; ++r) {
                float wv = (r < 4)  ? ((const float*)&w2a)[r & 3]
                         : (r < 8)  ? ((const float*)&w2b)[r & 3]
                         : (r < 12) ? ((const float*)&w2c)[r & 3]
                                    : ((const float*)&w2d)[r & 3];
                bacc = fmaf(fast_silu(C[r]), wv, bacc);
            }
            if (bt == 0) acc0 += bacc;
            else if (bt == 1) acc1 += bacc;
            else if (bt == 2) acc2 += bacc;
            else acc3 += bacc;
        }
        b2acc += b2v;
    }

    // merge the two h-halves (rows differ by +4 across hi), then add b2 once
    acc0 += __shfl_xor(acc0, 32);
    acc1 += __shfl_xor(acc1, 32);
    acc2 += __shfl_xor(acc2, 32);
    acc3 += __shfl_xor(acc3, 32);
    if (hi == 0) {
        atomicAdd(&out[(size_t)(0 * 32 + hl) * DOUT + j], acc0 + b2acc);
        atomicAdd(&out[(size_t)(1 * 32 + hl) * DOUT + j], acc1 + b2acc);
        atomicAdd(&out[(size_t)(2 * 32 + hl) * DOUT + j], acc2 + b2acc);
        atomicAdd(&out[(size_t)(3 * 32 + hl) * DOUT + j], acc3 + b2acc);
    }
}

// GLU gate + residual + BatchNorm(batch axis), one block per output column j.
__device__ __forceinline__ int shidx(int k, int b) { return (k << 7) + ((b + k) & 127); }

__global__ __launch_bounds__(128) void glu_bn_kernel(
    const float* __restrict__ h2,     // [128][128]
    const float* __restrict__ resid,  // [128][128]
    const float* __restrict__ g1w, const float* __restrict__ g1b,
    const float* __restrict__ g2w, const float* __restrict__ g2b,
    const float* __restrict__ bnw, const float* __restrict__ bnb,
    float* __restrict__ out)          // [128][128]
{
    __shared__ float sh[128 * 128];
    const int j   = blockIdx.x;
    const int tid = threadIdx.x;

    for (int b2 = 0; b2 < 128; ++b2)
        sh[shidx(tid, b2)] = h2[(size_t)b2 * 128 + tid];
    __syncthreads();

    const float* g1r = g1w + (size_t)j * 128;
    const float* g2r = g2w + (size_t)j * 128;
    float d1 = g1b[j], d2 = g2b[j];
    for (int k = 0; k < 128; ++k) {
        float hv = sh[shidx(k, tid)];
        d1 = fmaf(hv, g1r[k], d1);
        d2 = fmaf(hv, g2r[k], d2);
    }
    float sg = __builtin_amdgcn_rcpf(1.0f + __builtin_amdgcn_exp2f(d1 * -1.442695041f));
    float v  = sg * d2 + resid[(size_t)tid * 128 + j];

    float s = v, ss = v * v;
    #pragma unroll
    for (int m = 1; m < 64; m <<= 1) {
        s  += __shfl_xor(s,  m, 64);
        ss += __shfl_xor(ss, m, 64);
    }
    __syncthreads();
    if ((tid & 63) == 0) { sh[(tid >> 6) * 2] = s; sh[(tid >> 6) * 2 + 1] = ss; }
    __syncthreads();
    s  = sh[0] + sh[2];
    ss = sh[1] + sh[3];
    float mean = s * (1.0f / 128.0f);
    float var  = ss * (1.0f / 128.0f) - mean * mean;
    out[(size_t)tid * 128 + j] = (v - mean) * rsqrtf(var + 1e-5f) * bnw[j] + bnb[j];
}

extern "C" void kernel_launch(void* const* d_in, const int* in_sizes, int n_in,
                              void* d_out, int out_size, void* d_ws, size_t ws_size,
                              hipStream_t stream) {
    const float* x      = (const float*)d_in[0];
    const float* fc1_W1 = (const float*)d_in[1];
    const float* fc1_W2 = (const float*)d_in[2];
    const float* fc1_B1 = (const float*)d_in[3];
    const float* fc1_B2 = (const float*)d_in[4];
    const float* fc2_W1 = (const float*)d_in[5];
    const float* fc2_W2 = (const float*)d_in[6];
    const float* fc2_B1 = (const float*)d_in[7];
    const float* fc2_B2 = (const float*)d_in[8];
    const float* sk_W1  = (const float*)d_in[9];
    const float* sk_W2  = (const float*)d_in[10];
    const float* sk_B1  = (const float*)d_in[11];
    const float* sk_B2  = (const float*)d_in[12];
    const float* g1w    = (const float*)d_in[13];
    const float* g1b    = (const float*)d_in[14];
    const float* g2w    = (const float*)d_in[15];
    const float* g2b    = (const float*)d_in[16];
    const float* bnw    = (const float*)d_in[17];
    const float* bnb    = (const float*)d_in[18];
    float* out = (float*)d_out;

    float* ws    = (float*)d_ws;
    float* h1    = ws;                       // 128*256 f32
    float* h2    = h1 + 128 * 256;           // 128*128 f32
    float* resid = h2 + 128 * 128;           // 128*128 f32
    unsigned short* fxb = (unsigned short*)(resid + 128 * 128);  // 128*128*8 bf16
    unsigned short* fhb = fxb + 128 * 128 * 8;                   // 256*128*8 bf16

    hipMemsetAsync(h1, 0, (size_t)(128 * 256 + 2 * 128 * 128) * sizeof(float), stream);

    feats_kernel<<<dim3(64), 256, 0, stream>>>(x, fxb, 128, 0);

    kan_mfma<128, 256, 8><<<dim3(256, 4), 256, 0, stream>>>(
        fxb, fc1_W1, fc1_W2, fc1_B1, fc1_B2, h1);
    kan_mfma<128, 128, 8><<<dim3(128, 4), 256, 0, stream>>>(
        fxb, sk_W1, sk_W2, sk_B1, sk_B2, resid);

    feats_kernel<<<dim3(128), 256, 0, stream>>>(h1, fhb, 256, 1);

    kan_mfma<256, 128, 8><<<dim3(128, 8), 256, 0, stream>>>(
        fhb, fc2_W1, fc2_W2, fc2_B1, fc2_B2, h2);

    glu_bn_kernel<<<dim3(128), 128, 0, stream>>>(
        h2, resid, g1w, g1b, g2w, g2b, bnw, bnb, out);
}